// Round 13
// baseline (329.411 us; speedup 1.0000x reference)
//
#include <hip/hip_runtime.h>
#include <hip/hip_bf16.h>
#include <math.h>

using bf16 = __hip_bfloat16;
using frag8 = __attribute__((ext_vector_type(8))) short;
using f32x4 = __attribute__((ext_vector_type(4))) float;

#define LEAKY 0.2f
#define BN_EPS 1e-5f
#define NEGBIG -1e30f
#define BSHIFT 9

__device__ __forceinline__ float lrelu(float z){ return fmaxf(z, LEAKY * z); }
__device__ __forceinline__ float bflo(unsigned u){ return __uint_as_float(u << 16); }
__device__ __forceinline__ float bfhi(unsigned u){ return __uint_as_float(u & 0xffff0000u); }
// pack two floats into bf16 pair (RNE)
__device__ __forceinline__ unsigned pk(float a, float b){
  unsigned ua = __float_as_uint(a), ub = __float_as_uint(b);
  ua += 0x7fffu + ((ua >> 16) & 1u);
  ub += 0x7fffu + ((ub >> 16) & 1u);
  return (ua >> 16) | (ub & 0xffff0000u);
}
__device__ __forceinline__ unsigned short pk1(float a){
  unsigned ua = __float_as_uint(a);
  ua += 0x7fffu + ((ua >> 16) & 1u);
  return (unsigned short)(ua >> 16);
}
// dtype-adaptive load: isbf=1 -> bf16, else fp32
__device__ __forceinline__ float ldf(const void* p, size_t i, int isbf){
  if (isbf) return (float)((const bf16*)p)[i];
  return ((const float*)p)[i];
}

union U4F8 { uint4 u; frag8 f; };

// A-frag loaders: lane m=lane&15 -> node, k0 = s*32 + quad*8, 8 bf16 = 16B
__device__ __forceinline__ frag8 load_a_pairs(const unsigned* __restrict__ X2, int node, int k0){
  U4F8 v; v.u = *((const uint4*)(X2 + (size_t)node*64 + (k0 >> 1))); return v.f;
}
__device__ __forceinline__ frag8 load_a_f32(const float* __restrict__ X, int node, int k0){
  float4 q0 = *((const float4*)(X + (size_t)node*128 + k0));
  float4 q1 = *((const float4*)(X + (size_t)node*128 + k0 + 4));
  U4F8 v; v.u = make_uint4(pk(q0.x,q0.y), pk(q0.z,q0.w), pk(q1.x,q1.y), pk(q1.z,q1.w));
  return v.f;
}

// ------------- bcnt zero + fused input-dtype detector (single block) ----------
__global__ void init_detect(int* bcnt, const unsigned short* __restrict__ w1bits,
                            int* flag){
  __shared__ int cntr;
  if (threadIdx.x == 0) cntr = 0;
  bcnt[threadIdx.x] = 0;
  __syncthreads();
  unsigned u = w1bits[threadIdx.x * 2];
  int e = (u >> 7) & 0xff;
  atomicAdd(&cntr, (e >= 64 && e <= 140) ? 1 : 0);
  __syncthreads();
  if (threadIdx.x == 0) *flag = (cntr >= 160) ? 1 : 0;
}

// ------------- one-shot W transpose + wv = W·a precompute (bf16, global) ------
// WT1/WT2: [128 col][128 k]; WT3: [48 col][128 k] (cols 40..47 zero).
// WV*: al_src = (x·W)·a = x·(W·a) -> per head wv[k], stored B-fragment-ready.
__global__ __launch_bounds__(256) void wtrans(
    const void* __restrict__ W1, const void* __restrict__ W2,
    const void* __restrict__ W3,
    const void* __restrict__ as1, const void* __restrict__ ad1,
    const void* __restrict__ as2, const void* __restrict__ ad2,
    const void* __restrict__ as3, const void* __restrict__ ad3,
    const int* __restrict__ flagp,
    unsigned short* __restrict__ WT1, unsigned short* __restrict__ WT2,
    unsigned short* __restrict__ WT3,
    unsigned short* __restrict__ WVS1, unsigned short* __restrict__ WVD1,
    unsigned short* __restrict__ WVS2, unsigned short* __restrict__ WVD2,
    unsigned short* __restrict__ WV3S, unsigned short* __restrict__ WV3D){
  const int isbf = *flagp;
  const int g = blockIdx.x*256 + threadIdx.x;
  if (g < 16384){
    int k = g >> 7, nn = g & 127;
    unsigned short v1, v2;
    if (isbf){
      v1 = ((const unsigned short*)W1)[g];
      v2 = ((const unsigned short*)W2)[g];
    } else {
      v1 = pk1(((const float*)W1)[g]);
      v2 = pk1(((const float*)W2)[g]);
    }
    WT1[nn*128 + k] = v1;
    WT2[nn*128 + k] = v2;
  }
  if (g < 8192){
    int c = g & 63, k = g >> 6;
    if (c < 48){
      unsigned short v = 0;
      if (c < 40){
        if (isbf) v = ((const unsigned short*)W3)[k*40 + c];
        else      v = pk1(((const float*)W3)[k*40 + c]);
      }
      WT3[c*128 + k] = v;
    }
  }
  // wv dot products: 4 heads x 128 k x {src,dst} x {L1,L2} + 128 x 2 (L3)
  if (g < 2048){
    const int half = g >> 9;            // 0: layer1, ... (g<1024 L1, else L2)
    const int sd   = (g >> 8) & 1;      // within 512: but encode below
    (void)half; (void)sd;
    int idx = g & 511;                  // head*128 + k
    int head = idx >> 7, k = idx & 127;
    const void* W = (g < 1024) ? W1 : W2;
    const void* a = (g < 1024) ? (((g >> 9) & 1) ? ad1 : as1)
                               : (((g >> 9) & 1) ? ad2 : as2);
    float s = 0.f;
    for (int j = 0; j < 32; ++j){
      float wv = ldf(W, (size_t)k*128 + head*32 + j, isbf);
      s = fmaf(wv, ldf(a, head*32 + j, isbf), s);
    }
    unsigned short* out = (g < 512) ? WVS1 : (g < 1024) ? WVD1
                        : (g < 1536) ? WVS2 : WVD2;
    out[head*128 + k] = pk1(s);
  } else if (g < 2304){
    int idx = g - 2048;
    int sd = idx >> 7, k = idx & 127;
    const void* a = sd ? ad3 : as3;
    float s = 0.f;
    for (int j = 0; j < 40; ++j){
      float wv = ldf(W3, (size_t)k*40 + j, isbf);
      s = fmaf(wv, ldf(a, j, isbf), s);
    }
    (sd ? WV3D : WV3S)[k] = pk1(s);
  }
}

// ------------- bucket histogram only: LDS-reduced, no random atomics ----------
__global__ __launch_bounds__(256) void hist(const int* __restrict__ dst,
                                            int* bcnt, int e, int n){
  __shared__ int lb[256];
  const int t = threadIdx.x;
  lb[t] = 0;
  __syncthreads();
  const int c0 = blockIdx.x*4096;
  const int lim = min(4096, e - c0);
  for (int i = t; i < lim; i += 256){
    int d = dst[c0 + i];
    if ((unsigned)d < (unsigned)n)
      atomicAdd(&lb[min(d >> BSHIFT, 255)], 1);
  }
  __syncthreads();
  if (lb[t]) atomicAdd(&bcnt[t], lb[t]);
}

// ------------- bucket scan (single block, <=256 buckets) ----------------------
__global__ void bscan(const int* __restrict__ bcnt, int* bstart, int* bpos){
  __shared__ int s[256];
  int t = threadIdx.x;
  int v = bcnt[t];
  s[t] = v;
  __syncthreads();
  for (int off = 1; off < 256; off <<= 1){
    int x = (t >= off) ? s[t-off] : 0;
    __syncthreads();
    s[t] += x;
    __syncthreads();
  }
  int st = s[t] - v;
  bstart[t] = st;
  bpos[t] = st;
}

// ------------- bucket reservation scatter: no staging buffer ------------------
__global__ __launch_bounds__(256) void bres(const int* __restrict__ src,
                                            const int* __restrict__ dst,
                                            int* bpos, int2* __restrict__ ebuf,
                                            int e, int n){
  __shared__ int lh[256], gb[256];
  const int t = threadIdx.x;
  const int c0 = blockIdx.x*4096;
  if (c0 >= e) return;
  const int lim = min(4096, e - c0);
  lh[t] = 0;
  __syncthreads();
  int2 ev[16]; int bk[16];
  #pragma unroll
  for (int j = 0; j < 16; ++j){
    const int i = j*256 + t;
    const bool valid = i < lim;
    int s = 0, d = 0;
    if (valid){ s = src[c0 + i]; d = dst[c0 + i]; }
    ev[j] = make_int2(s, d);
    bk[j] = (valid && (unsigned)d < (unsigned)n) ? min(d >> BSHIFT, 255) : -1;
    if (bk[j] >= 0) atomicAdd(&lh[bk[j]], 1);
  }
  __syncthreads();
  const int v = lh[t];
  if (v) gb[t] = atomicAdd(&bpos[t], v);   // reserve contiguous run per bucket
  __syncthreads();
  lh[t] = 0;                                // reuse as cursor
  __syncthreads();
  #pragma unroll
  for (int j = 0; j < 16; ++j){
    if (bk[j] >= 0){
      int r = atomicAdd(&lh[bk[j]], 1);
      ebuf[gb[bk[j]] + r] = ev[j];
    }
  }
}

// ------------- per-bucket finalize: deg/scan/cnt/start/col, all LDS-local -----
__global__ __launch_bounds__(256) void bfinal(const int2* __restrict__ ebuf,
    const int* __restrict__ bstart, const int* __restrict__ bpos,
    int* __restrict__ cnt, int* __restrict__ start, int* __restrict__ col, int n){
  __shared__ int deg[512], off[512], ps[256];
  const int b = blockIdx.x, t = threadIdx.x;
  const int n0 = b << BSHIFT;
  const int e0 = bstart[b], e1 = bpos[b];
  deg[t] = 0; deg[t + 256] = 0;
  __syncthreads();
  for (int i = e0 + t; i < e1; i += 256)
    atomicAdd(&deg[ebuf[i].y - n0], 1);
  __syncthreads();
  int p = deg[2*t] + deg[2*t + 1];
  ps[t] = p;
  __syncthreads();
  for (int o = 1; o < 256; o <<= 1){
    int x = (t >= o) ? ps[t - o] : 0;
    __syncthreads();
    ps[t] += x;
    __syncthreads();
  }
  int ex = ps[t] - p;               // exclusive pair offset
  off[2*t]     = ex;
  off[2*t + 1] = ex + deg[2*t];
  __syncthreads();
  #pragma unroll
  for (int j = t; j < 512; j += 256){
    int node = n0 + j;
    if (node < n){ cnt[node] = deg[j]; start[node] = e0 + off[j]; }
  }
  __syncthreads();
  for (int i = e0 + t; i < e1; i += 256){
    int2 sd = ebuf[i];
    int r = atomicAdd(&off[sd.y - n0], 1);   // LDS cursor
    col[e0 + r] = sd.x;                      // lands in bucket's L2-local window
  }
}

// ---------------- MFMA GEMM 128x128, AL/AD via precomputed-wv MFMA column -----
// B-frags from global WT (L2-hot); AL/AD from acc2 = x·wv, no shuffle epilogue.
__global__ __launch_bounds__(256) void gemm_al_mfma(
    const void* __restrict__ X, int xkind,   // 0 = external input, 1 = packed pairs
    const unsigned short* __restrict__ WT,
    const unsigned short* __restrict__ WVS, const unsigned short* __restrict__ WVD,
    const int* __restrict__ flagp,
    unsigned* __restrict__ H2, float* __restrict__ AL, float* __restrict__ AD,
    int n, int ntiles)
{
  const int isbf = *flagp;
  const int t = threadIdx.x;
  const int w = t >> 6;          // wave == head
  const int lane = t & 63;
  const int m = lane & 15, quad = lane >> 4;

  frag8 bf[4][2];
  #pragma unroll
  for (int s = 0; s < 4; ++s)
    #pragma unroll
    for (int ct = 0; ct < 2; ++ct){
      int colc = w*32 + ct*16 + m;
      int k0 = s*32 + quad*8;
      U4F8 v; v.u = *((const uint4*)(WT + colc*128 + k0));
      bf[s][ct] = v.f;
    }
  // bf2: col0 = wv_src (head w), col1 = wv_dst, cols 2..15 zero
  frag8 bf2[4];
  #pragma unroll
  for (int s = 0; s < 4; ++s){
    U4F8 u; u.u = make_uint4(0,0,0,0);
    if (m < 2){
      const unsigned short* wv = (m == 0) ? (WVS + w*128) : (WVD + w*128);
      u.u = *((const uint4*)(wv + s*32 + quad*8));
    }
    bf2[s] = u.f;
  }
  const bool pairs = (xkind == 1) || isbf;  // bf16 rows == packed-pair layout

  for (int tile = blockIdx.x; tile < ntiles; tile += gridDim.x){
    const int mb = tile*16;
    int nodeA = mb + m; if (nodeA >= n) nodeA = n - 1;
    frag8 af[4];
    #pragma unroll
    for (int s = 0; s < 4; ++s){
      int k0 = s*32 + quad*8;
      af[s] = pairs ? load_a_pairs((const unsigned*)X, nodeA, k0)
                    : load_a_f32((const float*)X, nodeA, k0);
    }
    f32x4 acc0 = {0.f,0.f,0.f,0.f}, acc1 = {0.f,0.f,0.f,0.f}, acc2 = {0.f,0.f,0.f,0.f};
    #pragma unroll
    for (int s = 0; s < 4; ++s){
      acc0 = __builtin_amdgcn_mfma_f32_16x16x32_bf16(af[s], bf[s][0], acc0, 0,0,0);
      acc1 = __builtin_amdgcn_mfma_f32_16x16x32_bf16(af[s], bf[s][1], acc1, 0,0,0);
      acc2 = __builtin_amdgcn_mfma_f32_16x16x32_bf16(af[s], bf2[s],   acc2, 0,0,0);
    }
    #pragma unroll
    for (int r = 0; r < 4; ++r){
      int g = mb + quad*4 + r;
      float v0 = acc0[r], v1 = acc1[r];
      unsigned u0 = pk(v0, __shfl_xor(v0, 1));
      unsigned u1 = pk(v1, __shfl_xor(v1, 1));
      bool ok = g < n;
      if (((lane & 1) == 0) && ok){
        H2[(size_t)g*64 + w*16 + (m >> 1)]     = u0;
        H2[(size_t)g*64 + w*16 + 8 + (m >> 1)] = u1;
      }
      if (ok){
        if (m == 0)      AL[g*4 + w] = acc2[r];
        else if (m == 1) AD[g*4 + w] = acc2[r];
      }
    }
  }
}

// ---------------- MFMA GEMM 128x40, AL/AD via precomputed-wv MFMA column ------
__global__ __launch_bounds__(256) void gemm3_mfma(
    const unsigned* __restrict__ X2, const unsigned short* __restrict__ WT,
    const unsigned short* __restrict__ WV3S, const unsigned short* __restrict__ WV3D,
    unsigned* __restrict__ H3, float* __restrict__ AL, float* __restrict__ AD,
    int n, int ntiles)
{
  const int t = threadIdx.x;
  const int w = t >> 6;
  const int lane = t & 63;
  const int m = lane & 15, quad = lane >> 4;

  frag8 bf[4][3];
  #pragma unroll
  for (int ct = 0; ct < 3; ++ct){
    int colc = ct*16 + m;
    #pragma unroll
    for (int s = 0; s < 4; ++s){
      int k0 = s*32 + quad*8;
      U4F8 v; v.u = *((const uint4*)(WT + colc*128 + k0));
      bf[ct? s : s][ct] = v.f;
    }
  }
  frag8 bf2[4];
  #pragma unroll
  for (int s = 0; s < 4; ++s){
    U4F8 u; u.u = make_uint4(0,0,0,0);
    if (m < 2){
      const unsigned short* wv = (m == 0) ? WV3S : WV3D;
      u.u = *((const uint4*)(wv + s*32 + quad*8));
    }
    bf2[s] = u.f;
  }

  for (int tg = blockIdx.x; tg*4 < ntiles; tg += gridDim.x){
    const int tile = tg*4 + w;
    if (tile >= ntiles) continue;
    const int mb = tile*16;
    int nodeA = mb + m; if (nodeA >= n) nodeA = n - 1;
    frag8 af[4];
    #pragma unroll
    for (int s = 0; s < 4; ++s)
      af[s] = load_a_pairs(X2, nodeA, s*32 + quad*8);
    f32x4 acc[3]; f32x4 acc2 = {0.f,0.f,0.f,0.f};
    #pragma unroll
    for (int ct = 0; ct < 3; ++ct) acc[ct] = (f32x4){0.f,0.f,0.f,0.f};
    #pragma unroll
    for (int s = 0; s < 4; ++s){
      acc[0] = __builtin_amdgcn_mfma_f32_16x16x32_bf16(af[s], bf[s][0], acc[0], 0,0,0);
      acc[1] = __builtin_amdgcn_mfma_f32_16x16x32_bf16(af[s], bf[s][1], acc[1], 0,0,0);
      acc[2] = __builtin_amdgcn_mfma_f32_16x16x32_bf16(af[s], bf[s][2], acc[2], 0,0,0);
      acc2   = __builtin_amdgcn_mfma_f32_16x16x32_bf16(af[s], bf2[s],   acc2,   0,0,0);
    }
    #pragma unroll
    for (int r = 0; r < 4; ++r){
      int g = mb + quad*4 + r;
      bool ok = g < n;
      #pragma unroll
      for (int ct = 0; ct < 3; ++ct){
        float v = acc[ct][r];
        unsigned u = pk(v, __shfl_xor(v, 1));
        bool stok = ((lane & 1) == 0) && ok && (ct < 2 || m < 8);
        if (stok) H3[(size_t)g*20 + ct*8 + (m >> 1)] = u;
      }
      if (ok){
        if (m == 0)      AL[g] = acc2[r];
        else if (m == 1) AD[g] = acc2[r];
      }
    }
  }
}

// ---- aggregation (layers 1,2): wave/node, cooperative exp, pipelined col -----
__global__ __launch_bounds__(256) void agg4(
    const unsigned* __restrict__ H2,
    const float* __restrict__ ALf, const float* __restrict__ ADf,
    const int* __restrict__ cnt, const int* __restrict__ start, const int* __restrict__ col,
    const void* __restrict__ bias, const void* __restrict__ bng, const void* __restrict__ bnb,
    const void* __restrict__ bnm,  const void* __restrict__ bnv,
    const int* __restrict__ flagp,
    unsigned* __restrict__ Hout, int n)
{
  const int isbf = *flagp;
  const int wave = threadIdx.x >> 6;
  const int lane = threadIdx.x & 63;
  const int node = blockIdx.x*4 + wave;
  if (node >= n) return;
  const int head = lane >> 4;
  const float ad = ADf[node*4 + head];
  const int eu = (lane >> 2) & 7;          // cooperative: my edge slot
  const int eh = lane & 3;                  // cooperative: my head slot
  const float ade = ADf[node*4 + eh];       // AD for my cooperative head
  const int base = __builtin_amdgcn_readfirstlane(start[node]);
  const int deg  = __builtin_amdgcn_readfirstlane(cnt[node]);

  float accL, accH, l;
  {
    float e = __expf(lrelu(ALf[node*4 + head] + ad));
    unsigned h = H2[(size_t)node*64 + lane];
    l = e; accL = e * bflo(h); accH = e * bfhi(h);
  }

  const int nb8 = deg >> 3, rem = deg & 7;
  int sva[8], svb[8];
  if (nb8){
    #pragma unroll
    for (int u = 0; u < 8; ++u) sva[u] = col[base + u];
  } else if (rem){
    const int lim = rem - 1;
    #pragma unroll
    for (int u = 0; u < 8; ++u) sva[u] = col[base + (u < lim ? u : lim)];
  }
  for (int b = 0; b < nb8; ++b){
    unsigned hv[8];
    #pragma unroll
    for (int u = 0; u < 8; ++u) hv[u] = H2[(size_t)sva[u]*64 + lane];
    float ave = ALf[sva[eu]*4 + eh];
    // prefetch next block's col while gathers are in flight
    if (b + 1 < nb8){
      const int nbb = base + (b + 1)*8;
      #pragma unroll
      for (int u = 0; u < 8; ++u) svb[u] = col[nbb + u];
    } else if (rem){
      const int tb = base + nb8*8, lim = rem - 1;
      #pragma unroll
      for (int u = 0; u < 8; ++u) svb[u] = col[tb + (u < lim ? u : lim)];
    }
    float ew = __expf(lrelu(ave + ade));
    #pragma unroll
    for (int u = 0; u < 8; ++u){
      float e = __shfl(ew, (u << 2) + head);   // ds_bpermute, off the VALU pipe
      l += e;
      accL = fmaf(e, bflo(hv[u]), accL);
      accH = fmaf(e, bfhi(hv[u]), accH);
    }
    #pragma unroll
    for (int u = 0; u < 8; ++u) sva[u] = svb[u];
  }
  if (rem){                                 // masked cooperative tail block
    unsigned hv[8];
    #pragma unroll
    for (int u = 0; u < 8; ++u) hv[u] = H2[(size_t)sva[u]*64 + lane];
    float ave = ALf[sva[eu]*4 + eh];
    float ew = __expf(lrelu(ave + ade));
    #pragma unroll
    for (int u = 0; u < 8; ++u){
      float e = (u < rem) ? __shfl(ew, (u << 2) + head) : 0.f;
      l += e;
      accL = fmaf(e, bflo(hv[u]), accL);
      accH = fmaf(e, bfhi(hv[u]), accH);
    }
  }

  const float rl = 1.f / l;
  const int c0 = 2*lane, c1 = c0 + 1;
  float v0 = fmaxf(accL*rl + ldf(bias,c0,isbf), 0.f);
  v0 = (v0 - ldf(bnm,c0,isbf)) * rsqrtf(ldf(bnv,c0,isbf) + BN_EPS) * ldf(bng,c0,isbf) + ldf(bnb,c0,isbf);
  float v1 = fmaxf(accH*rl + ldf(bias,c1,isbf), 0.f);
  v1 = (v1 - ldf(bnm,c1,isbf)) * rsqrtf(ldf(bnv,c1,isbf) + BN_EPS) * ldf(bng,c1,isbf) + ldf(bnb,c1,isbf);
  Hout[(size_t)node*64 + lane] = pk(v0, v1);
}

// ---- aggregation (layer 3) + log_softmax: 2 nodes/wave (32 lanes each) -------
__global__ __launch_bounds__(256) void agg1(
    const unsigned* __restrict__ H3,
    const float* __restrict__ AL, const float* __restrict__ AD,
    const int* __restrict__ cnt, const int* __restrict__ start, const int* __restrict__ col,
    const void* __restrict__ b3, const int* __restrict__ flagp,
    void* __restrict__ out, int n)
{
  const int isbf = *flagp;
  const int t = threadIdx.x;
  const int p = t & 31;                    // lane within 32-lane node group
  const int node = blockIdx.x*8 + (t >> 5);
  if (node >= n) return;
  const float ad = AD[node];
  const bool act = p < 20;
  const int eu = p & 7;                    // cooperative edge slot
  const int base = start[node], deg = cnt[node];

  float accL, accH, l;
  {
    float e = __expf(lrelu(AL[node] + ad));
    unsigned h = act ? H3[(size_t)node*20 + p] : 0u;
    l = e; accL = e * bflo(h); accH = e * bfhi(h);
  }

  const int nb8 = deg >> 3, rem = deg & 7;
  int sva[8], svb[8];
  if (nb8){
    #pragma unroll
    for (int u = 0; u < 8; ++u) sva[u] = col[base + u];
  } else if (rem){
    const int lim = rem - 1;
    #pragma unroll
    for (int u = 0; u < 8; ++u) sva[u] = col[base + (u < lim ? u : lim)];
  }
  for (int b = 0; b < nb8; ++b){
    unsigned hv[8];
    #pragma unroll
    for (int u = 0; u < 8; ++u) hv[u] = act ? H3[(size_t)sva[u]*20 + p] : 0u;
    float ave = AL[sva[eu]];
    if (b + 1 < nb8){
      const int nbb = base + (b + 1)*8;
      #pragma unroll
      for (int u = 0; u < 8; ++u) svb[u] = col[nbb + u];
    } else if (rem){
      const int tb = base + nb8*8, lim = rem - 1;
      #pragma unroll
      for (int u = 0; u < 8; ++u) svb[u] = col[tb + (u < lim ? u : lim)];
    }
    float ew = __expf(lrelu(ave + ad));
    #pragma unroll
    for (int u = 0; u < 8; ++u){
      float e = __shfl(ew, u, 32);         // segment-relative within 32 lanes
      l += e;
      accL = fmaf(e, bflo(hv[u]), accL);
      accH = fmaf(e, bfhi(hv[u]), accH);
    }
    #pragma unroll
    for (int u = 0; u < 8; ++u) sva[u] = svb[u];
  }
  if (rem){
    unsigned hv[8];
    #pragma unroll
    for (int u = 0; u < 8; ++u) hv[u] = act ? H3[(size_t)sva[u]*20 + p] : 0u;
    float ave = AL[sva[eu]];
    float ew = __expf(lrelu(ave + ad));
    #pragma unroll
    for (int u = 0; u < 8; ++u){
      float e = (u < rem) ? __shfl(ew, u, 32) : 0.f;
      l += e;
      accL = fmaf(e, bflo(hv[u]), accL);
      accH = fmaf(e, bfhi(hv[u]), accH);
    }
  }

  const float rl = 1.f / l;
  const int c0 = 2*p;
  float z0 = act ? (accL*rl + ldf(b3, c0,     isbf)) : NEGBIG;
  float z1 = act ? (accH*rl + ldf(b3, c0 + 1, isbf)) : NEGBIG;
  float mx = fmaxf(z0, z1);
  #pragma unroll
  for (int off = 1; off < 32; off <<= 1) mx = fmaxf(mx, __shfl_xor(mx, off));
  float pp = act ? (__expf(z0 - mx) + __expf(z1 - mx)) : 0.f;
  float sum = pp;
  #pragma unroll
  for (int off = 1; off < 32; off <<= 1) sum += __shfl_xor(sum, off);
  if (act){
    float lg = __logf(sum);
    float r0 = z0 - mx - lg, r1 = z1 - mx - lg;
    if (isbf) ((unsigned*)out)[(size_t)node*20 + p] = pk(r0, r1);
    else      ((float2*)out)[(size_t)node*20 + p] = make_float2(r0, r1);
  }
}

// ---------------- launch ----------------
extern "C" void kernel_launch(void* const* d_in, const int* in_sizes, int n_in,
                              void* d_out, int out_size, void* d_ws, size_t ws_size,
                              hipStream_t stream)
{
  (void)n_in; (void)out_size; (void)ws_size;
  const void* x    = d_in[0];
  const int*  ei   = (const int*)d_in[1];
  const void* W1   = d_in[2];
  const void* as1  = d_in[3];
  const void* ad1  = d_in[4];
  const void* b1   = d_in[5];
  const void* W2   = d_in[6];
  const void* as2  = d_in[7];
  const void* ad2  = d_in[8];
  const void* b2   = d_in[9];
  const void* W3   = d_in[10];
  const void* as3  = d_in[11];
  const void* ad3  = d_in[12];
  const void* b3   = d_in[13];
  const void* bn1g = d_in[14];
  const void* bn1b = d_in[15];
  const void* bn1m = d_in[16];
  const void* bn1v = d_in[17];
  const void* bn2g = d_in[18];
  const void* bn2b = d_in[19];
  const void* bn2m = d_in[20];
  const void* bn2v = d_in[21];

  const int N  = in_sizes[0] / 128;
  const int E  = in_sizes[1] / 2;
  const int ntiles = (N + 15) / 16;

  char* w = (char*)d_ws;
  size_t off = 0;
  auto alloc = [&](size_t bytes)->char*{
    char* p = w + off; off = (off + bytes + 255) & ~(size_t)255; return p;
  };
  unsigned* H2A = (unsigned*)alloc((size_t)N*64*4);   // packed bf16 pairs
  unsigned* H2B = (unsigned*)alloc((size_t)N*64*4);
  unsigned* H3p = (unsigned*)alloc((size_t)N*20*4);
  float* AL   = (float*)alloc((size_t)N*4*4);
  float* AD   = (float*)alloc((size_t)N*4*4);
  int*   cnt   = (int*)alloc((size_t)N*4);
  int*   start = (int*)alloc((size_t)N*4);
  int*   col   = (int*)alloc((size_t)E*4);
  int2*  ebuf  = (int2*)alloc((size_t)E*8);
  unsigned short* WT1 = (unsigned short*)alloc(16384*2);
  unsigned short* WT2 = (unsigned short*)alloc(16384*2);
  unsigned short* WT3 = (unsigned short*)alloc(48*128*2);
  unsigned short* WVS1 = (unsigned short*)alloc(512*2);
  unsigned short* WVD1 = (unsigned short*)alloc(512*2);
  unsigned short* WVS2 = (unsigned short*)alloc(512*2);
  unsigned short* WVD2 = (unsigned short*)alloc(512*2);
  unsigned short* WV3S = (unsigned short*)alloc(128*2);
  unsigned short* WV3D = (unsigned short*)alloc(128*2);
  int*   bcnt  = (int*)alloc(1024);
  int*   bstart= (int*)alloc(1024);
  int*   bpos  = (int*)alloc(1024);
  int*   flag  = (int*)alloc(256);

  const int* srcp = ei;
  const int* dstp = ei + E;

  const int nbCH = (E + 4095)/4096;
  const int NB = (N + 511) >> BSHIFT;     // buckets of 512 nodes
  const int bb = (N + 3)/4;               // agg4: 1 node/wave, 4 waves/block
  const int bb1 = (N + 7)/8;              // agg1: 2 nodes/wave, 8 nodes/block
  int g1 = ntiles;                        // 1 tile/block (no LDS, cheap setup)
  int g3 = (ntiles + 3)/4; if (g3 > 800) g3 = 800;

  // CSR build: bucket counting sort, zero random device atomics
  init_detect<<<1,256,0,stream>>>(bcnt, (const unsigned short*)W1, flag);
  wtrans<<<64,256,0,stream>>>(W1, W2, W3, as1, ad1, as2, ad2, as3, ad3, flag,
                              WT1, WT2, WT3, WVS1, WVD1, WVS2, WVD2, WV3S, WV3D);
  hist<<<nbCH,256,0,stream>>>(dstp, bcnt, E, N);
  bscan<<<1,256,0,stream>>>(bcnt, bstart, bpos);
  bres<<<nbCH,256,0,stream>>>(srcp, dstp, bpos, ebuf, E, N);
  bfinal<<<NB,256,0,stream>>>(ebuf, bstart, bpos, cnt, start, col, N);

  // layer 1
  gemm_al_mfma<<<g1,256,0,stream>>>(x, 0, WT1, WVS1, WVD1, flag, H2A, AL, AD, N, ntiles);
  agg4<<<bb,256,0,stream>>>(H2A, AL, AD, cnt, start, col,
                            b1, bn1g, bn1b, bn1m, bn1v, flag, H2B, N);
  // layer 2
  gemm_al_mfma<<<g1,256,0,stream>>>(H2B, 1, WT2, WVS2, WVD2, flag, H2A, AL, AD, N, ntiles);
  agg4<<<bb,256,0,stream>>>(H2A, AL, AD, cnt, start, col,
                            b2, bn2g, bn2b, bn2m, bn2v, flag, H2B, N);
  // layer 3
  gemm3_mfma<<<g3,256,0,stream>>>((const unsigned*)H2B, WT3, WV3S, WV3D, H3p, AL, AD, N, ntiles);
  agg1<<<bb1,256,0,stream>>>(H3p, AL, AD, cnt, start, col, b3, flag, d_out, N);
}

// Round 14
// 328.038 us; speedup vs baseline: 1.0042x; 1.0042x over previous
//
#include <hip/hip_runtime.h>
#include <hip/hip_bf16.h>
#include <math.h>

using bf16 = __hip_bfloat16;
using frag8 = __attribute__((ext_vector_type(8))) short;
using f32x4 = __attribute__((ext_vector_type(4))) float;

#define LEAKY 0.2f
#define BN_EPS 1e-5f
#define NEGBIG -1e30f
#define BSHIFT 9

__device__ __forceinline__ float lrelu(float z){ return fmaxf(z, LEAKY * z); }
__device__ __forceinline__ float bflo(unsigned u){ return __uint_as_float(u << 16); }
__device__ __forceinline__ float bfhi(unsigned u){ return __uint_as_float(u & 0xffff0000u); }
// pack two floats into bf16 pair (RNE)
__device__ __forceinline__ unsigned pk(float a, float b){
  unsigned ua = __float_as_uint(a), ub = __float_as_uint(b);
  ua += 0x7fffu + ((ua >> 16) & 1u);
  ub += 0x7fffu + ((ub >> 16) & 1u);
  return (ua >> 16) | (ub & 0xffff0000u);
}
__device__ __forceinline__ unsigned short pk1(float a){
  unsigned ua = __float_as_uint(a);
  ua += 0x7fffu + ((ua >> 16) & 1u);
  return (unsigned short)(ua >> 16);
}
// dtype-adaptive load: isbf=1 -> bf16, else fp32
__device__ __forceinline__ float ldf(const void* p, size_t i, int isbf){
  if (isbf) return (float)((const bf16*)p)[i];
  return ((const float*)p)[i];
}

union U4F8 { uint4 u; frag8 f; };

// A-frag loaders: lane m=lane&15 -> node, k0 = s*32 + quad*8, 8 bf16 = 16B
__device__ __forceinline__ frag8 load_a_pairs(const unsigned* __restrict__ X2, int node, int k0){
  U4F8 v; v.u = *((const uint4*)(X2 + (size_t)node*64 + (k0 >> 1))); return v.f;
}
__device__ __forceinline__ frag8 load_a_f32(const float* __restrict__ X, int node, int k0){
  float4 q0 = *((const float4*)(X + (size_t)node*128 + k0));
  float4 q1 = *((const float4*)(X + (size_t)node*128 + k0 + 4));
  U4F8 v; v.u = make_uint4(pk(q0.x,q0.y), pk(q0.z,q0.w), pk(q1.x,q1.y), pk(q1.z,q1.w));
  return v.f;
}

// ------------- bcnt zero + fused input-dtype detector (single block) ----------
__global__ void init_detect(int* bcnt, const unsigned short* __restrict__ w1bits,
                            int* flag){
  __shared__ int cntr;
  if (threadIdx.x == 0) cntr = 0;
  bcnt[threadIdx.x] = 0;
  __syncthreads();
  unsigned u = w1bits[threadIdx.x * 2];
  int e = (u >> 7) & 0xff;
  atomicAdd(&cntr, (e >= 64 && e <= 140) ? 1 : 0);
  __syncthreads();
  if (threadIdx.x == 0) *flag = (cntr >= 160) ? 1 : 0;
}

// ------------- one-shot W transpose: W^T into global (bf16), shared by all ----
__global__ __launch_bounds__(256) void wtrans(
    const void* __restrict__ W1, const void* __restrict__ W2,
    const void* __restrict__ W3, const int* __restrict__ flagp,
    unsigned short* __restrict__ WT1, unsigned short* __restrict__ WT2,
    unsigned short* __restrict__ WT3){
  const int isbf = *flagp;
  const int g = blockIdx.x*256 + threadIdx.x;
  if (g < 16384){
    int k = g >> 7, nn = g & 127;
    unsigned short v1, v2;
    if (isbf){
      v1 = ((const unsigned short*)W1)[g];
      v2 = ((const unsigned short*)W2)[g];
    } else {
      v1 = pk1(((const float*)W1)[g]);
      v2 = pk1(((const float*)W2)[g]);
    }
    WT1[nn*128 + k] = v1;
    WT2[nn*128 + k] = v2;
  }
  if (g < 8192){
    int c = g & 63, k = g >> 6;
    if (c < 48){
      unsigned short v = 0;
      if (c < 40){
        if (isbf) v = ((const unsigned short*)W3)[k*40 + c];
        else      v = pk1(((const float*)W3)[k*40 + c]);
      }
      WT3[c*128 + k] = v;
    }
  }
}

// ------------- bucket histogram only: LDS-reduced, no random atomics ----------
__global__ __launch_bounds__(256) void hist(const int* __restrict__ dst,
                                            int* bcnt, int e, int n){
  __shared__ int lb[256];
  const int t = threadIdx.x;
  lb[t] = 0;
  __syncthreads();
  const int c0 = blockIdx.x*4096;
  const int lim = min(4096, e - c0);
  for (int i = t; i < lim; i += 256){
    int d = dst[c0 + i];
    if ((unsigned)d < (unsigned)n)
      atomicAdd(&lb[min(d >> BSHIFT, 255)], 1);
  }
  __syncthreads();
  if (lb[t]) atomicAdd(&bcnt[t], lb[t]);
}

// ------------- bucket scan (single block, <=256 buckets) ----------------------
__global__ void bscan(const int* __restrict__ bcnt, int* bstart, int* bpos){
  __shared__ int s[256];
  int t = threadIdx.x;
  int v = bcnt[t];
  s[t] = v;
  __syncthreads();
  for (int off = 1; off < 256; off <<= 1){
    int x = (t >= off) ? s[t-off] : 0;
    __syncthreads();
    s[t] += x;
    __syncthreads();
  }
  int st = s[t] - v;
  bstart[t] = st;
  bpos[t] = st;
}

// ------------- bucket reservation scatter: no staging buffer ------------------
__global__ __launch_bounds__(256) void bres(const int* __restrict__ src,
                                            const int* __restrict__ dst,
                                            int* bpos, int2* __restrict__ ebuf,
                                            int e, int n){
  __shared__ int lh[256], gb[256];
  const int t = threadIdx.x;
  const int c0 = blockIdx.x*4096;
  if (c0 >= e) return;
  const int lim = min(4096, e - c0);
  lh[t] = 0;
  __syncthreads();
  int2 ev[16]; int bk[16];
  #pragma unroll
  for (int j = 0; j < 16; ++j){
    const int i = j*256 + t;
    const bool valid = i < lim;
    int s = 0, d = 0;
    if (valid){ s = src[c0 + i]; d = dst[c0 + i]; }
    ev[j] = make_int2(s, d);
    bk[j] = (valid && (unsigned)d < (unsigned)n) ? min(d >> BSHIFT, 255) : -1;
    if (bk[j] >= 0) atomicAdd(&lh[bk[j]], 1);
  }
  __syncthreads();
  const int v = lh[t];
  if (v) gb[t] = atomicAdd(&bpos[t], v);   // reserve contiguous run per bucket
  __syncthreads();
  lh[t] = 0;                                // reuse as cursor
  __syncthreads();
  #pragma unroll
  for (int j = 0; j < 16; ++j){
    if (bk[j] >= 0){
      int r = atomicAdd(&lh[bk[j]], 1);
      ebuf[gb[bk[j]] + r] = ev[j];
    }
  }
}

// ------------- per-bucket finalize: deg/scan/cnt/start/col, all LDS-local -----
__global__ __launch_bounds__(256) void bfinal(const int2* __restrict__ ebuf,
    const int* __restrict__ bstart, const int* __restrict__ bpos,
    int* __restrict__ cnt, int* __restrict__ start, int* __restrict__ col, int n){
  __shared__ int deg[512], off[512], ps[256];
  const int b = blockIdx.x, t = threadIdx.x;
  const int n0 = b << BSHIFT;
  const int e0 = bstart[b], e1 = bpos[b];
  deg[t] = 0; deg[t + 256] = 0;
  __syncthreads();
  for (int i = e0 + t; i < e1; i += 256)
    atomicAdd(&deg[ebuf[i].y - n0], 1);
  __syncthreads();
  int p = deg[2*t] + deg[2*t + 1];
  ps[t] = p;
  __syncthreads();
  for (int o = 1; o < 256; o <<= 1){
    int x = (t >= o) ? ps[t - o] : 0;
    __syncthreads();
    ps[t] += x;
    __syncthreads();
  }
  int ex = ps[t] - p;               // exclusive pair offset
  off[2*t]     = ex;
  off[2*t + 1] = ex + deg[2*t];
  __syncthreads();
  #pragma unroll
  for (int j = t; j < 512; j += 256){
    int node = n0 + j;
    if (node < n){ cnt[node] = deg[j]; start[node] = e0 + off[j]; }
  }
  __syncthreads();
  for (int i = e0 + t; i < e1; i += 256){
    int2 sd = ebuf[i];
    int r = atomicAdd(&off[sd.y - n0], 1);   // LDS cursor
    col[e0 + r] = sd.x;                      // lands in bucket's L2-local window
  }
}

// ---------------- MFMA GEMM 128x128 + fused al (layers 1,2) --------------------
// B-fragments loaded directly from pre-transposed global WT (L2-hot, 32KB).
__global__ __launch_bounds__(256) void gemm_al_mfma(
    const void* __restrict__ X, int xkind,   // 0 = external input, 1 = packed pairs
    const unsigned short* __restrict__ WT,
    const void* __restrict__ Wsrc, const void* __restrict__ Wdst,
    const int* __restrict__ flagp,
    unsigned* __restrict__ H2, float* __restrict__ AL, float* __restrict__ AD,
    int n, int ntiles)
{
  const int isbf = *flagp;
  const int t = threadIdx.x;
  const int w = t >> 6;          // wave == head
  const int lane = t & 63;
  const int m = lane & 15, quad = lane >> 4;

  frag8 bf[4][2];
  #pragma unroll
  for (int s = 0; s < 4; ++s)
    #pragma unroll
    for (int ct = 0; ct < 2; ++ct){
      int colc = w*32 + ct*16 + m;
      int k0 = s*32 + quad*8;
      U4F8 v; v.u = *((const uint4*)(WT + colc*128 + k0));
      bf[s][ct] = v.f;
    }
  float avv[2], dvv[2];
  #pragma unroll
  for (int ct = 0; ct < 2; ++ct){
    int colc = w*32 + ct*16 + m;
    avv[ct] = ldf(Wsrc, colc, isbf);
    dvv[ct] = ldf(Wdst, colc, isbf);
  }
  const bool pairs = (xkind == 1) || isbf;  // bf16 rows == packed-pair layout

  for (int tile = blockIdx.x; tile < ntiles; tile += gridDim.x){
    const int mb = tile*16;
    int nodeA = mb + m; if (nodeA >= n) nodeA = n - 1;
    frag8 af[4];
    #pragma unroll
    for (int s = 0; s < 4; ++s){
      int k0 = s*32 + quad*8;
      af[s] = pairs ? load_a_pairs((const unsigned*)X, nodeA, k0)
                    : load_a_f32((const float*)X, nodeA, k0);
    }
    f32x4 acc0 = {0.f,0.f,0.f,0.f}, acc1 = {0.f,0.f,0.f,0.f};
    #pragma unroll
    for (int s = 0; s < 4; ++s){
      acc0 = __builtin_amdgcn_mfma_f32_16x16x32_bf16(af[s], bf[s][0], acc0, 0,0,0);
      acc1 = __builtin_amdgcn_mfma_f32_16x16x32_bf16(af[s], bf[s][1], acc1, 0,0,0);
    }
    #pragma unroll
    for (int r = 0; r < 4; ++r){
      int g = mb + quad*4 + r;
      float v0 = acc0[r], v1 = acc1[r];
      unsigned u0 = pk(v0, __shfl_xor(v0, 1));
      unsigned u1 = pk(v1, __shfl_xor(v1, 1));
      bool ok = g < n;
      if (((lane & 1) == 0) && ok){
        H2[(size_t)g*64 + w*16 + (m >> 1)]     = u0;
        H2[(size_t)g*64 + w*16 + 8 + (m >> 1)] = u1;
      }
      float s1 = v0*avv[0] + v1*avv[1];
      float s2 = v0*dvv[0] + v1*dvv[1];
      s1 += __shfl_xor(s1,1); s1 += __shfl_xor(s1,2); s1 += __shfl_xor(s1,4); s1 += __shfl_xor(s1,8);
      s2 += __shfl_xor(s2,1); s2 += __shfl_xor(s2,2); s2 += __shfl_xor(s2,4); s2 += __shfl_xor(s2,8);
      if (m == 0 && ok){ AL[g*4 + w] = s1; AD[g*4 + w] = s2; }
    }
  }
}

// ---------------- MFMA GEMM 128x40 + fused al (layer 3) -----------------------
__global__ __launch_bounds__(256) void gemm3_mfma(
    const unsigned* __restrict__ X2, const unsigned short* __restrict__ WT,
    const void* __restrict__ Wsrc, const void* __restrict__ Wdst,
    const int* __restrict__ flagp,
    unsigned* __restrict__ H3, float* __restrict__ AL, float* __restrict__ AD,
    int n, int ntiles)
{
  const int isbf = *flagp;
  const int t = threadIdx.x;
  const int w = t >> 6;
  const int lane = t & 63;
  const int m = lane & 15, quad = lane >> 4;

  frag8 bf[4][3];
  float avv[3], dvv[3];
  #pragma unroll
  for (int ct = 0; ct < 3; ++ct){
    int colc = ct*16 + m;
    #pragma unroll
    for (int s = 0; s < 4; ++s){
      int k0 = s*32 + quad*8;
      U4F8 v; v.u = *((const uint4*)(WT + colc*128 + k0));
      bf[s][ct] = v.f;
    }
    avv[ct] = (colc < 40) ? ldf(Wsrc, colc, isbf) : 0.f;
    dvv[ct] = (colc < 40) ? ldf(Wdst, colc, isbf) : 0.f;
  }

  for (int tg = blockIdx.x; tg*4 < ntiles; tg += gridDim.x){
    const int tile = tg*4 + w;
    if (tile >= ntiles) continue;
    const int mb = tile*16;
    int nodeA = mb + m; if (nodeA >= n) nodeA = n - 1;
    frag8 af[4];
    #pragma unroll
    for (int s = 0; s < 4; ++s)
      af[s] = load_a_pairs(X2, nodeA, s*32 + quad*8);
    f32x4 acc[3];
    #pragma unroll
    for (int ct = 0; ct < 3; ++ct) acc[ct] = (f32x4){0.f,0.f,0.f,0.f};
    #pragma unroll
    for (int s = 0; s < 4; ++s){
      acc[0] = __builtin_amdgcn_mfma_f32_16x16x32_bf16(af[s], bf[s][0], acc[0], 0,0,0);
      acc[1] = __builtin_amdgcn_mfma_f32_16x16x32_bf16(af[s], bf[s][1], acc[1], 0,0,0);
      acc[2] = __builtin_amdgcn_mfma_f32_16x16x32_bf16(af[s], bf[s][2], acc[2], 0,0,0);
    }
    #pragma unroll
    for (int r = 0; r < 4; ++r){
      int g = mb + quad*4 + r;
      bool ok = g < n;
      float ps = 0.f, pd = 0.f;
      #pragma unroll
      for (int ct = 0; ct < 3; ++ct){
        float v = acc[ct][r];
        ps += v*avv[ct]; pd += v*dvv[ct];
        unsigned u = pk(v, __shfl_xor(v, 1));
        bool stok = ((lane & 1) == 0) && ok && (ct < 2 || m < 8);
        if (stok) H3[(size_t)g*20 + ct*8 + (m >> 1)] = u;
      }
      ps += __shfl_xor(ps,1); ps += __shfl_xor(ps,2); ps += __shfl_xor(ps,4); ps += __shfl_xor(ps,8);
      pd += __shfl_xor(pd,1); pd += __shfl_xor(pd,2); pd += __shfl_xor(pd,4); pd += __shfl_xor(pd,8);
      if (m == 0 && ok){ AL[g] = ps; AD[g] = pd; }
    }
  }
}

// ---- aggregation (layers 1,2): wave/node, cooperative exp, 2-deep pipeline ---
// indices (scalar s_load) prefetched 2 blocks ahead; H2/AL data 1 block ahead:
// gather latency overlaps the previous block's exp+fma compute in-wave.
__global__ __launch_bounds__(256) void agg4(
    const unsigned* __restrict__ H2,
    const float* __restrict__ ALf, const float* __restrict__ ADf,
    const int* __restrict__ cnt, const int* __restrict__ start, const int* __restrict__ col,
    const void* __restrict__ bias, const void* __restrict__ bng, const void* __restrict__ bnb,
    const void* __restrict__ bnm,  const void* __restrict__ bnv,
    const int* __restrict__ flagp,
    unsigned* __restrict__ Hout, int n)
{
  const int isbf = *flagp;
  const int wave = threadIdx.x >> 6;
  const int lane = threadIdx.x & 63;
  const int node = blockIdx.x*4 + wave;
  if (node >= n) return;
  const int head = lane >> 4;
  const float ad = ADf[node*4 + head];
  const int eu = (lane >> 2) & 7;          // cooperative: my edge slot
  const int eh = lane & 3;                  // cooperative: my head slot
  const float ade = ADf[node*4 + eh];       // AD for my cooperative head
  const int base = __builtin_amdgcn_readfirstlane(start[node]);
  const int deg  = __builtin_amdgcn_readfirstlane(cnt[node]);

  float accL, accH, l;
  {
    float e = __expf(lrelu(ALf[node*4 + head] + ad));
    unsigned h = H2[(size_t)node*64 + lane];
    l = e; accL = e * bflo(h); accH = e * bfhi(h);
  }

  const int nb8 = deg >> 3, rem = deg & 7;
  const int nbt = nb8 + (rem ? 1 : 0);
  if (nbt){
    auto ldidx = [&](int b, int* d){
      if (b < nb8){
        const int o = base + b*8;
        #pragma unroll
        for (int u = 0; u < 8; ++u) d[u] = col[o + u];
      } else if (b == nb8 && rem){
        const int o = base + nb8*8, lim = rem - 1;
        #pragma unroll
        for (int u = 0; u < 8; ++u) d[u] = col[o + (u < lim ? u : lim)];
      }
      // else: keep previous (safe dummy)
    };
    int svc[8], svn[8];
    unsigned hvc[8];
    ldidx(0, svc);
    #pragma unroll
    for (int u = 0; u < 8; ++u) hvc[u] = H2[(size_t)svc[u]*64 + lane];
    float avec = ALf[svc[eu]*4 + eh];
    #pragma unroll
    for (int u = 0; u < 8; ++u) svn[u] = svc[u];
    ldidx(1, svn);

    for (int b = 0; b < nb8; ++b){
      unsigned hvn[8];
      #pragma unroll
      for (int u = 0; u < 8; ++u) hvn[u] = H2[(size_t)svn[u]*64 + lane];
      float aven = ALf[svn[eu]*4 + eh];
      int svp[8];
      #pragma unroll
      for (int u = 0; u < 8; ++u) svp[u] = svn[u];
      ldidx(b + 2, svp);
      float ew = __expf(lrelu(avec + ade));
      #pragma unroll
      for (int u = 0; u < 8; ++u){
        float e = __shfl(ew, (u << 2) + head);   // ds_bpermute, off the VALU pipe
        l += e;
        accL = fmaf(e, bflo(hvc[u]), accL);
        accH = fmaf(e, bfhi(hvc[u]), accH);
      }
      #pragma unroll
      for (int u = 0; u < 8; ++u){ svn[u] = svp[u]; hvc[u] = hvn[u]; }
      avec = aven;
    }
    if (rem){                               // masked tail: data already in hvc
      float ew = __expf(lrelu(avec + ade));
      #pragma unroll
      for (int u = 0; u < 8; ++u){
        float e = (u < rem) ? __shfl(ew, (u << 2) + head) : 0.f;
        l += e;
        accL = fmaf(e, bflo(hvc[u]), accL);
        accH = fmaf(e, bfhi(hvc[u]), accH);
      }
    }
  }

  const float rl = 1.f / l;
  const int c0 = 2*lane, c1 = c0 + 1;
  float v0 = fmaxf(accL*rl + ldf(bias,c0,isbf), 0.f);
  v0 = (v0 - ldf(bnm,c0,isbf)) * rsqrtf(ldf(bnv,c0,isbf) + BN_EPS) * ldf(bng,c0,isbf) + ldf(bnb,c0,isbf);
  float v1 = fmaxf(accH*rl + ldf(bias,c1,isbf), 0.f);
  v1 = (v1 - ldf(bnm,c1,isbf)) * rsqrtf(ldf(bnv,c1,isbf) + BN_EPS) * ldf(bng,c1,isbf) + ldf(bnb,c1,isbf);
  Hout[(size_t)node*64 + lane] = pk(v0, v1);
}

// ---- aggregation (layer 3) + log_softmax: 2 nodes/wave, 2-deep pipeline ------
__global__ __launch_bounds__(256) void agg1(
    const unsigned* __restrict__ H3,
    const float* __restrict__ AL, const float* __restrict__ AD,
    const int* __restrict__ cnt, const int* __restrict__ start, const int* __restrict__ col,
    const void* __restrict__ b3, const int* __restrict__ flagp,
    void* __restrict__ out, int n)
{
  const int isbf = *flagp;
  const int t = threadIdx.x;
  const int p = t & 31;                    // lane within 32-lane node group
  const int node = blockIdx.x*8 + (t >> 5);
  if (node >= n) return;
  const float ad = AD[node];
  const bool act = p < 20;
  const int eu = p & 7;                    // cooperative edge slot
  const int base = start[node], deg = cnt[node];

  float accL, accH, l;
  {
    float e = __expf(lrelu(AL[node] + ad));
    unsigned h = act ? H3[(size_t)node*20 + p] : 0u;
    l = e; accL = e * bflo(h); accH = e * bfhi(h);
  }

  const int nb8 = deg >> 3, rem = deg & 7;
  const int nbt = nb8 + (rem ? 1 : 0);
  if (nbt){
    auto ldidx = [&](int b, int* d){
      if (b < nb8){
        const int o = base + b*8;
        #pragma unroll
        for (int u = 0; u < 8; ++u) d[u] = col[o + u];
      } else if (b == nb8 && rem){
        const int o = base + nb8*8, lim = rem - 1;
        #pragma unroll
        for (int u = 0; u < 8; ++u) d[u] = col[o + (u < lim ? u : lim)];
      }
    };
    int svc[8], svn[8];
    unsigned hvc[8];
    ldidx(0, svc);
    #pragma unroll
    for (int u = 0; u < 8; ++u) hvc[u] = act ? H3[(size_t)svc[u]*20 + p] : 0u;
    float avec = AL[svc[eu]];
    #pragma unroll
    for (int u = 0; u < 8; ++u) svn[u] = svc[u];
    ldidx(1, svn);

    for (int b = 0; b < nb8; ++b){
      unsigned hvn[8];
      #pragma unroll
      for (int u = 0; u < 8; ++u) hvn[u] = act ? H3[(size_t)svn[u]*20 + p] : 0u;
      float aven = AL[svn[eu]];
      int svp[8];
      #pragma unroll
      for (int u = 0; u < 8; ++u) svp[u] = svn[u];
      ldidx(b + 2, svp);
      float ew = __expf(lrelu(avec + ad));
      #pragma unroll
      for (int u = 0; u < 8; ++u){
        float e = __shfl(ew, u, 32);       // segment-relative within 32 lanes
        l += e;
        accL = fmaf(e, bflo(hvc[u]), accL);
        accH = fmaf(e, bfhi(hvc[u]), accH);
      }
      #pragma unroll
      for (int u = 0; u < 8; ++u){ svn[u] = svp[u]; hvc[u] = hvn[u]; }
      avec = aven;
    }
    if (rem){
      float ew = __expf(lrelu(avec + ad));
      #pragma unroll
      for (int u = 0; u < 8; ++u){
        float e = (u < rem) ? __shfl(ew, u, 32) : 0.f;
        l += e;
        accL = fmaf(e, bflo(hvc[u]), accL);
        accH = fmaf(e, bfhi(hvc[u]), accH);
      }
    }
  }

  const float rl = 1.f / l;
  const int c0 = 2*p;
  float z0 = act ? (accL*rl + ldf(b3, c0,     isbf)) : NEGBIG;
  float z1 = act ? (accH*rl + ldf(b3, c0 + 1, isbf)) : NEGBIG;
  float mx = fmaxf(z0, z1);
  #pragma unroll
  for (int off = 1; off < 32; off <<= 1) mx = fmaxf(mx, __shfl_xor(mx, off));
  float pp = act ? (__expf(z0 - mx) + __expf(z1 - mx)) : 0.f;
  float sum = pp;
  #pragma unroll
  for (int off = 1; off < 32; off <<= 1) sum += __shfl_xor(sum, off);
  if (act){
    float lg = __logf(sum);
    float r0 = z0 - mx - lg, r1 = z1 - mx - lg;
    if (isbf) ((unsigned*)out)[(size_t)node*20 + p] = pk(r0, r1);
    else      ((float2*)out)[(size_t)node*20 + p] = make_float2(r0, r1);
  }
}

// ---------------- launch ----------------
extern "C" void kernel_launch(void* const* d_in, const int* in_sizes, int n_in,
                              void* d_out, int out_size, void* d_ws, size_t ws_size,
                              hipStream_t stream)
{
  (void)n_in; (void)out_size; (void)ws_size;
  const void* x    = d_in[0];
  const int*  ei   = (const int*)d_in[1];
  const void* W1   = d_in[2];
  const void* as1  = d_in[3];
  const void* ad1  = d_in[4];
  const void* b1   = d_in[5];
  const void* W2   = d_in[6];
  const void* as2  = d_in[7];
  const void* ad2  = d_in[8];
  const void* b2   = d_in[9];
  const void* W3   = d_in[10];
  const void* as3  = d_in[11];
  const void* ad3  = d_in[12];
  const void* b3   = d_in[13];
  const void* bn1g = d_in[14];
  const void* bn1b = d_in[15];
  const void* bn1m = d_in[16];
  const void* bn1v = d_in[17];
  const void* bn2g = d_in[18];
  const void* bn2b = d_in[19];
  const void* bn2m = d_in[20];
  const void* bn2v = d_in[21];

  const int N  = in_sizes[0] / 128;
  const int E  = in_sizes[1] / 2;
  const int ntiles = (N + 15) / 16;

  char* w = (char*)d_ws;
  size_t off = 0;
  auto alloc = [&](size_t bytes)->char*{
    char* p = w + off; off = (off + bytes + 255) & ~(size_t)255; return p;
  };
  unsigned* H2A = (unsigned*)alloc((size_t)N*64*4);   // packed bf16 pairs
  unsigned* H2B = (unsigned*)alloc((size_t)N*64*4);
  unsigned* H3p = (unsigned*)alloc((size_t)N*20*4);
  float* AL   = (float*)alloc((size_t)N*4*4);
  float* AD   = (float*)alloc((size_t)N*4*4);
  int*   cnt   = (int*)alloc((size_t)N*4);
  int*   start = (int*)alloc((size_t)N*4);
  int*   col   = (int*)alloc((size_t)E*4);
  int2*  ebuf  = (int2*)alloc((size_t)E*8);
  unsigned short* WT1 = (unsigned short*)alloc(16384*2);
  unsigned short* WT2 = (unsigned short*)alloc(16384*2);
  unsigned short* WT3 = (unsigned short*)alloc(48*128*2);
  int*   bcnt  = (int*)alloc(1024);
  int*   bstart= (int*)alloc(1024);
  int*   bpos  = (int*)alloc(1024);
  int*   flag  = (int*)alloc(256);

  const int* srcp = ei;
  const int* dstp = ei + E;

  const int nbCH = (E + 4095)/4096;
  const int NB = (N + 511) >> BSHIFT;     // buckets of 512 nodes
  const int bb = (N + 3)/4;               // agg4: 1 node/wave, 4 waves/block
  const int bb1 = (N + 7)/8;              // agg1: 2 nodes/wave, 8 nodes/block
  int g1 = ntiles;                        // 1 tile/block (no LDS, cheap setup)
  int g3 = (ntiles + 3)/4; if (g3 > 800) g3 = 800;

  // CSR build: bucket counting sort, zero random device atomics
  init_detect<<<1,256,0,stream>>>(bcnt, (const unsigned short*)W1, flag);
  wtrans<<<64,256,0,stream>>>(W1, W2, W3, flag, WT1, WT2, WT3);
  hist<<<nbCH,256,0,stream>>>(dstp, bcnt, E, N);
  bscan<<<1,256,0,stream>>>(bcnt, bstart, bpos);
  bres<<<nbCH,256,0,stream>>>(srcp, dstp, bpos, ebuf, E, N);
  bfinal<<<NB,256,0,stream>>>(ebuf, bstart, bpos, cnt, start, col, N);

  // layer 1
  gemm_al_mfma<<<g1,256,0,stream>>>(x, 0, WT1, as1, ad1, flag, H2A, AL, AD, N, ntiles);
  agg4<<<bb,256,0,stream>>>(H2A, AL, AD, cnt, start, col,
                            b1, bn1g, bn1b, bn1m, bn1v, flag, H2B, N);
  // layer 2
  gemm_al_mfma<<<g1,256,0,stream>>>(H2B, 1, WT2, as2, ad2, flag, H2A, AL, AD, N, ntiles);
  agg4<<<bb,256,0,stream>>>(H2A, AL, AD, cnt, start, col,
                            b2, bn2g, bn2b, bn2m, bn2v, flag, H2B, N);
  // layer 3
  gemm3_mfma<<<g3,256,0,stream>>>((const unsigned*)H2B, WT3, as3, ad3, flag, H3p, AL, AD, N, ntiles);
  agg1<<<bb1,256,0,stream>>>(H3p, AL, AD, cnt, start, col, b3, flag, d_out, N);
}

// Round 15
// 320.298 us; speedup vs baseline: 1.0285x; 1.0242x over previous
//
#include <hip/hip_runtime.h>
#include <hip/hip_bf16.h>
#include <math.h>

using bf16 = __hip_bfloat16;
using frag8 = __attribute__((ext_vector_type(8))) short;
using f32x4 = __attribute__((ext_vector_type(4))) float;

#define LEAKY 0.2f
#define BN_EPS 1e-5f
#define NEGBIG -1e30f
#define BSHIFT 9

__device__ __forceinline__ float lrelu(float z){ return fmaxf(z, LEAKY * z); }
__device__ __forceinline__ float bflo(unsigned u){ return __uint_as_float(u << 16); }
__device__ __forceinline__ float bfhi(unsigned u){ return __uint_as_float(u & 0xffff0000u); }
// pack two floats into bf16 pair (RNE)
__device__ __forceinline__ unsigned pk(float a, float b){
  unsigned ua = __float_as_uint(a), ub = __float_as_uint(b);
  ua += 0x7fffu + ((ua >> 16) & 1u);
  ub += 0x7fffu + ((ub >> 16) & 1u);
  return (ua >> 16) | (ub & 0xffff0000u);
}
__device__ __forceinline__ unsigned short pk1(float a){
  unsigned ua = __float_as_uint(a);
  ua += 0x7fffu + ((ua >> 16) & 1u);
  return (unsigned short)(ua >> 16);
}
// dtype-adaptive load: isbf=1 -> bf16, else fp32
__device__ __forceinline__ float ldf(const void* p, size_t i, int isbf){
  if (isbf) return (float)((const bf16*)p)[i];
  return ((const float*)p)[i];
}

union U4F8 { uint4 u; frag8 f; };

// A-frag loaders: lane m=lane&15 -> node, k0 = s*32 + quad*8, 8 bf16 = 16B
__device__ __forceinline__ frag8 load_a_pairs(const unsigned* __restrict__ X2, int node, int k0){
  U4F8 v; v.u = *((const uint4*)(X2 + (size_t)node*64 + (k0 >> 1))); return v.f;
}
__device__ __forceinline__ frag8 load_a_f32(const float* __restrict__ X, int node, int k0){
  float4 q0 = *((const float4*)(X + (size_t)node*128 + k0));
  float4 q1 = *((const float4*)(X + (size_t)node*128 + k0 + 4));
  U4F8 v; v.u = make_uint4(pk(q0.x,q0.y), pk(q0.z,q0.w), pk(q1.x,q1.y), pk(q1.z,q1.w));
  return v.f;
}

// ------------- bcnt zero + fused input-dtype detector (single block) ----------
__global__ void init_detect(int* bcnt, const unsigned short* __restrict__ w1bits,
                            int* flag){
  __shared__ int cntr;
  if (threadIdx.x == 0) cntr = 0;
  bcnt[threadIdx.x] = 0;
  __syncthreads();
  unsigned u = w1bits[threadIdx.x * 2];
  int e = (u >> 7) & 0xff;
  atomicAdd(&cntr, (e >= 64 && e <= 140) ? 1 : 0);
  __syncthreads();
  if (threadIdx.x == 0) *flag = (cntr >= 160) ? 1 : 0;
}

// ------------- one-shot W transpose: W^T into global (bf16), shared by all ----
__global__ __launch_bounds__(256) void wtrans(
    const void* __restrict__ W1, const void* __restrict__ W2,
    const void* __restrict__ W3, const int* __restrict__ flagp,
    unsigned short* __restrict__ WT1, unsigned short* __restrict__ WT2,
    unsigned short* __restrict__ WT3){
  const int isbf = *flagp;
  const int g = blockIdx.x*256 + threadIdx.x;
  if (g < 16384){
    int k = g >> 7, nn = g & 127;
    unsigned short v1, v2;
    if (isbf){
      v1 = ((const unsigned short*)W1)[g];
      v2 = ((const unsigned short*)W2)[g];
    } else {
      v1 = pk1(((const float*)W1)[g]);
      v2 = pk1(((const float*)W2)[g]);
    }
    WT1[nn*128 + k] = v1;
    WT2[nn*128 + k] = v2;
  }
  if (g < 8192){
    int c = g & 63, k = g >> 6;
    if (c < 48){
      unsigned short v = 0;
      if (c < 40){
        if (isbf) v = ((const unsigned short*)W3)[k*40 + c];
        else      v = pk1(((const float*)W3)[k*40 + c]);
      }
      WT3[c*128 + k] = v;
    }
  }
}

// ------------- bucket histogram only: LDS-reduced, no random atomics ----------
__global__ __launch_bounds__(256) void hist(const int* __restrict__ dst,
                                            int* bcnt, int e, int n){
  __shared__ int lb[256];
  const int t = threadIdx.x;
  lb[t] = 0;
  __syncthreads();
  const int c0 = blockIdx.x*4096;
  const int lim = min(4096, e - c0);
  for (int i = t; i < lim; i += 256){
    int d = dst[c0 + i];
    if ((unsigned)d < (unsigned)n)
      atomicAdd(&lb[min(d >> BSHIFT, 255)], 1);
  }
  __syncthreads();
  if (lb[t]) atomicAdd(&bcnt[t], lb[t]);
}

// ------------- bucket scan (single block, <=256 buckets) ----------------------
__global__ void bscan(const int* __restrict__ bcnt, int* bstart, int* bpos){
  __shared__ int s[256];
  int t = threadIdx.x;
  int v = bcnt[t];
  s[t] = v;
  __syncthreads();
  for (int off = 1; off < 256; off <<= 1){
    int x = (t >= off) ? s[t-off] : 0;
    __syncthreads();
    s[t] += x;
    __syncthreads();
  }
  int st = s[t] - v;
  bstart[t] = st;
  bpos[t] = st;
}

// ------------- bucket reservation scatter: no staging buffer ------------------
__global__ __launch_bounds__(256) void bres(const int* __restrict__ src,
                                            const int* __restrict__ dst,
                                            int* bpos, int2* __restrict__ ebuf,
                                            int e, int n){
  __shared__ int lh[256], gb[256];
  const int t = threadIdx.x;
  const int c0 = blockIdx.x*4096;
  if (c0 >= e) return;
  const int lim = min(4096, e - c0);
  lh[t] = 0;
  __syncthreads();
  int2 ev[16]; int bk[16];
  #pragma unroll
  for (int j = 0; j < 16; ++j){
    const int i = j*256 + t;
    const bool valid = i < lim;
    int s = 0, d = 0;
    if (valid){ s = src[c0 + i]; d = dst[c0 + i]; }
    ev[j] = make_int2(s, d);
    bk[j] = (valid && (unsigned)d < (unsigned)n) ? min(d >> BSHIFT, 255) : -1;
    if (bk[j] >= 0) atomicAdd(&lh[bk[j]], 1);
  }
  __syncthreads();
  const int v = lh[t];
  if (v) gb[t] = atomicAdd(&bpos[t], v);   // reserve contiguous run per bucket
  __syncthreads();
  lh[t] = 0;                                // reuse as cursor
  __syncthreads();
  #pragma unroll
  for (int j = 0; j < 16; ++j){
    if (bk[j] >= 0){
      int r = atomicAdd(&lh[bk[j]], 1);
      ebuf[gb[bk[j]] + r] = ev[j];
    }
  }
}

// ------------- per-bucket finalize: deg/scan/cnt/start/col, all LDS-local -----
__global__ __launch_bounds__(256) void bfinal(const int2* __restrict__ ebuf,
    const int* __restrict__ bstart, const int* __restrict__ bpos,
    int* __restrict__ cnt, int* __restrict__ start, int* __restrict__ col, int n){
  __shared__ int deg[512], off[512], ps[256];
  const int b = blockIdx.x, t = threadIdx.x;
  const int n0 = b << BSHIFT;
  const int e0 = bstart[b], e1 = bpos[b];
  deg[t] = 0; deg[t + 256] = 0;
  __syncthreads();
  for (int i = e0 + t; i < e1; i += 256)
    atomicAdd(&deg[ebuf[i].y - n0], 1);
  __syncthreads();
  int p = deg[2*t] + deg[2*t + 1];
  ps[t] = p;
  __syncthreads();
  for (int o = 1; o < 256; o <<= 1){
    int x = (t >= o) ? ps[t - o] : 0;
    __syncthreads();
    ps[t] += x;
    __syncthreads();
  }
  int ex = ps[t] - p;               // exclusive pair offset
  off[2*t]     = ex;
  off[2*t + 1] = ex + deg[2*t];
  __syncthreads();
  #pragma unroll
  for (int j = t; j < 512; j += 256){
    int node = n0 + j;
    if (node < n){ cnt[node] = deg[j]; start[node] = e0 + off[j]; }
  }
  __syncthreads();
  for (int i = e0 + t; i < e1; i += 256){
    int2 sd = ebuf[i];
    int r = atomicAdd(&off[sd.y - n0], 1);   // LDS cursor
    col[e0 + r] = sd.x;                      // lands in bucket's L2-local window
  }
}

// ---------------- MFMA GEMM 128x128 + fused al (layers 1,2) --------------------
// B-fragments loaded directly from pre-transposed global WT (L2-hot, 32KB) --
// no LDS, no barrier, no staging: occupancy is VGPR-bound. 1 tile/block.
__global__ __launch_bounds__(256) void gemm_al_mfma(
    const void* __restrict__ X, int xkind,   // 0 = external input, 1 = packed pairs
    const unsigned short* __restrict__ WT,
    const void* __restrict__ Wsrc, const void* __restrict__ Wdst,
    const int* __restrict__ flagp,
    unsigned* __restrict__ H2, float* __restrict__ AL, float* __restrict__ AD,
    int n, int ntiles)
{
  const int isbf = *flagp;
  const int t = threadIdx.x;
  const int w = t >> 6;          // wave == head
  const int lane = t & 63;
  const int m = lane & 15, quad = lane >> 4;

  frag8 bf[4][2];
  #pragma unroll
  for (int s = 0; s < 4; ++s)
    #pragma unroll
    for (int ct = 0; ct < 2; ++ct){
      int colc = w*32 + ct*16 + m;
      int k0 = s*32 + quad*8;
      U4F8 v; v.u = *((const uint4*)(WT + colc*128 + k0));
      bf[s][ct] = v.f;
    }
  float avv[2], dvv[2];
  #pragma unroll
  for (int ct = 0; ct < 2; ++ct){
    int colc = w*32 + ct*16 + m;
    avv[ct] = ldf(Wsrc, colc, isbf);
    dvv[ct] = ldf(Wdst, colc, isbf);
  }
  const bool pairs = (xkind == 1) || isbf;  // bf16 rows == packed-pair layout

  for (int tile = blockIdx.x; tile < ntiles; tile += gridDim.x){
    const int mb = tile*16;
    int nodeA = mb + m; if (nodeA >= n) nodeA = n - 1;
    frag8 af[4];
    #pragma unroll
    for (int s = 0; s < 4; ++s){
      int k0 = s*32 + quad*8;
      af[s] = pairs ? load_a_pairs((const unsigned*)X, nodeA, k0)
                    : load_a_f32((const float*)X, nodeA, k0);
    }
    f32x4 acc0 = {0.f,0.f,0.f,0.f}, acc1 = {0.f,0.f,0.f,0.f};
    #pragma unroll
    for (int s = 0; s < 4; ++s){
      acc0 = __builtin_amdgcn_mfma_f32_16x16x32_bf16(af[s], bf[s][0], acc0, 0,0,0);
      acc1 = __builtin_amdgcn_mfma_f32_16x16x32_bf16(af[s], bf[s][1], acc1, 0,0,0);
    }
    #pragma unroll
    for (int r = 0; r < 4; ++r){
      int g = mb + quad*4 + r;
      float v0 = acc0[r], v1 = acc1[r];
      unsigned u0 = pk(v0, __shfl_xor(v0, 1));
      unsigned u1 = pk(v1, __shfl_xor(v1, 1));
      bool ok = g < n;
      if (((lane & 1) == 0) && ok){
        H2[(size_t)g*64 + w*16 + (m >> 1)]     = u0;
        H2[(size_t)g*64 + w*16 + 8 + (m >> 1)] = u1;
      }
      float s1 = v0*avv[0] + v1*avv[1];
      float s2 = v0*dvv[0] + v1*dvv[1];
      s1 += __shfl_xor(s1,1); s1 += __shfl_xor(s1,2); s1 += __shfl_xor(s1,4); s1 += __shfl_xor(s1,8);
      s2 += __shfl_xor(s2,1); s2 += __shfl_xor(s2,2); s2 += __shfl_xor(s2,4); s2 += __shfl_xor(s2,8);
      if (m == 0 && ok){ AL[g*4 + w] = s1; AD[g*4 + w] = s2; }
    }
  }
}

// ---------------- MFMA GEMM 128x40 + fused al (layer 3) -----------------------
__global__ __launch_bounds__(256) void gemm3_mfma(
    const unsigned* __restrict__ X2, const unsigned short* __restrict__ WT,
    const void* __restrict__ Wsrc, const void* __restrict__ Wdst,
    const int* __restrict__ flagp,
    unsigned* __restrict__ H3, float* __restrict__ AL, float* __restrict__ AD,
    int n, int ntiles)
{
  const int isbf = *flagp;
  const int t = threadIdx.x;
  const int w = t >> 6;
  const int lane = t & 63;
  const int m = lane & 15, quad = lane >> 4;

  frag8 bf[4][3];
  float avv[3], dvv[3];
  #pragma unroll
  for (int ct = 0; ct < 3; ++ct){
    int colc = ct*16 + m;
    #pragma unroll
    for (int s = 0; s < 4; ++s){
      int k0 = s*32 + quad*8;
      U4F8 v; v.u = *((const uint4*)(WT + colc*128 + k0));
      bf[s][ct] = v.f;
    }
    avv[ct] = (colc < 40) ? ldf(Wsrc, colc, isbf) : 0.f;
    dvv[ct] = (colc < 40) ? ldf(Wdst, colc, isbf) : 0.f;
  }

  for (int tg = blockIdx.x; tg*4 < ntiles; tg += gridDim.x){
    const int tile = tg*4 + w;
    if (tile >= ntiles) continue;
    const int mb = tile*16;
    int nodeA = mb + m; if (nodeA >= n) nodeA = n - 1;
    frag8 af[4];
    #pragma unroll
    for (int s = 0; s < 4; ++s)
      af[s] = load_a_pairs(X2, nodeA, s*32 + quad*8);
    f32x4 acc[3];
    #pragma unroll
    for (int ct = 0; ct < 3; ++ct) acc[ct] = (f32x4){0.f,0.f,0.f,0.f};
    #pragma unroll
    for (int s = 0; s < 4; ++s){
      acc[0] = __builtin_amdgcn_mfma_f32_16x16x32_bf16(af[s], bf[s][0], acc[0], 0,0,0);
      acc[1] = __builtin_amdgcn_mfma_f32_16x16x32_bf16(af[s], bf[s][1], acc[1], 0,0,0);
      acc[2] = __builtin_amdgcn_mfma_f32_16x16x32_bf16(af[s], bf[s][2], acc[2], 0,0,0);
    }
    #pragma unroll
    for (int r = 0; r < 4; ++r){
      int g = mb + quad*4 + r;
      bool ok = g < n;
      float ps = 0.f, pd = 0.f;
      #pragma unroll
      for (int ct = 0; ct < 3; ++ct){
        float v = acc[ct][r];
        ps += v*avv[ct]; pd += v*dvv[ct];
        unsigned u = pk(v, __shfl_xor(v, 1));
        bool stok = ((lane & 1) == 0) && ok && (ct < 2 || m < 8);
        if (stok) H3[(size_t)g*20 + ct*8 + (m >> 1)] = u;
      }
      ps += __shfl_xor(ps,1); ps += __shfl_xor(ps,2); ps += __shfl_xor(ps,4); ps += __shfl_xor(ps,8);
      pd += __shfl_xor(pd,1); pd += __shfl_xor(pd,2); pd += __shfl_xor(pd,4); pd += __shfl_xor(pd,8);
      if (m == 0 && ok){ AL[g] = ps; AD[g] = pd; }
    }
  }
}

// ---- aggregation (layers 1,2): wave/node, cooperative exp, pipelined col -----
// base/deg are wave-uniform: readfirstlane forces the scalar pipe for col
// loads, freeing the vector-memory queue for H2 gathers.
__global__ __launch_bounds__(256) void agg4(
    const unsigned* __restrict__ H2,
    const float* __restrict__ ALf, const float* __restrict__ ADf,
    const int* __restrict__ cnt, const int* __restrict__ start, const int* __restrict__ col,
    const void* __restrict__ bias, const void* __restrict__ bng, const void* __restrict__ bnb,
    const void* __restrict__ bnm,  const void* __restrict__ bnv,
    const int* __restrict__ flagp,
    unsigned* __restrict__ Hout, int n)
{
  const int isbf = *flagp;
  const int wave = threadIdx.x >> 6;
  const int lane = threadIdx.x & 63;
  const int node = blockIdx.x*4 + wave;
  if (node >= n) return;
  const int head = lane >> 4;
  const float ad = ADf[node*4 + head];
  const int eu = (lane >> 2) & 7;          // cooperative: my edge slot
  const int eh = lane & 3;                  // cooperative: my head slot
  const float ade = ADf[node*4 + eh];       // AD for my cooperative head
  const int base = __builtin_amdgcn_readfirstlane(start[node]);
  const int deg  = __builtin_amdgcn_readfirstlane(cnt[node]);

  float accL, accH, l;
  {
    float e = __expf(lrelu(ALf[node*4 + head] + ad));
    unsigned h = H2[(size_t)node*64 + lane];
    l = e; accL = e * bflo(h); accH = e * bfhi(h);
  }

  const int nb8 = deg >> 3, rem = deg & 7;
  int sva[8], svb[8];
  if (nb8){
    #pragma unroll
    for (int u = 0; u < 8; ++u) sva[u] = col[base + u];
  } else if (rem){
    const int lim = rem - 1;
    #pragma unroll
    for (int u = 0; u < 8; ++u) sva[u] = col[base + (u < lim ? u : lim)];
  }
  for (int b = 0; b < nb8; ++b){
    unsigned hv[8];
    #pragma unroll
    for (int u = 0; u < 8; ++u) hv[u] = H2[(size_t)sva[u]*64 + lane];
    float ave = ALf[sva[eu]*4 + eh];
    // prefetch next block's col while gathers are in flight
    if (b + 1 < nb8){
      const int nbb = base + (b + 1)*8;
      #pragma unroll
      for (int u = 0; u < 8; ++u) svb[u] = col[nbb + u];
    } else if (rem){
      const int tb = base + nb8*8, lim = rem - 1;
      #pragma unroll
      for (int u = 0; u < 8; ++u) svb[u] = col[tb + (u < lim ? u : lim)];
    }
    float ew = __expf(lrelu(ave + ade));
    #pragma unroll
    for (int u = 0; u < 8; ++u){
      float e = __shfl(ew, (u << 2) + head);   // ds_bpermute, off the VALU pipe
      l += e;
      accL = fmaf(e, bflo(hv[u]), accL);
      accH = fmaf(e, bfhi(hv[u]), accH);
    }
    #pragma unroll
    for (int u = 0; u < 8; ++u) sva[u] = svb[u];
  }
  if (rem){                                 // masked cooperative tail block
    unsigned hv[8];
    #pragma unroll
    for (int u = 0; u < 8; ++u) hv[u] = H2[(size_t)sva[u]*64 + lane];
    float ave = ALf[sva[eu]*4 + eh];
    float ew = __expf(lrelu(ave + ade));
    #pragma unroll
    for (int u = 0; u < 8; ++u){
      float e = (u < rem) ? __shfl(ew, (u << 2) + head) : 0.f;
      l += e;
      accL = fmaf(e, bflo(hv[u]), accL);
      accH = fmaf(e, bfhi(hv[u]), accH);
    }
  }

  const float rl = 1.f / l;
  const int c0 = 2*lane, c1 = c0 + 1;
  float v0 = fmaxf(accL*rl + ldf(bias,c0,isbf), 0.f);
  v0 = (v0 - ldf(bnm,c0,isbf)) * rsqrtf(ldf(bnv,c0,isbf) + BN_EPS) * ldf(bng,c0,isbf) + ldf(bnb,c0,isbf);
  float v1 = fmaxf(accH*rl + ldf(bias,c1,isbf), 0.f);
  v1 = (v1 - ldf(bnm,c1,isbf)) * rsqrtf(ldf(bnv,c1,isbf) + BN_EPS) * ldf(bng,c1,isbf) + ldf(bnb,c1,isbf);
  Hout[(size_t)node*64 + lane] = pk(v0, v1);
}

// ---- aggregation (layer 3) + log_softmax: 2 nodes/wave (32 lanes each) -------
__global__ __launch_bounds__(256) void agg1(
    const unsigned* __restrict__ H3,
    const float* __restrict__ AL, const float* __restrict__ AD,
    const int* __restrict__ cnt, const int* __restrict__ start, const int* __restrict__ col,
    const void* __restrict__ b3, const int* __restrict__ flagp,
    void* __restrict__ out, int n)
{
  const int isbf = *flagp;
  const int t = threadIdx.x;
  const int p = t & 31;                    // lane within 32-lane node group
  const int node = blockIdx.x*8 + (t >> 5);
  if (node >= n) return;
  const float ad = AD[node];
  const bool act = p < 20;
  const int eu = p & 7;                    // cooperative edge slot
  const int base = start[node], deg = cnt[node];

  float accL, accH, l;
  {
    float e = __expf(lrelu(AL[node] + ad));
    unsigned h = act ? H3[(size_t)node*20 + p] : 0u;
    l = e; accL = e * bflo(h); accH = e * bfhi(h);
  }

  const int nb8 = deg >> 3, rem = deg & 7;
  int sva[8], svb[8];
  if (nb8){
    #pragma unroll
    for (int u = 0; u < 8; ++u) sva[u] = col[base + u];
  } else if (rem){
    const int lim = rem - 1;
    #pragma unroll
    for (int u = 0; u < 8; ++u) sva[u] = col[base + (u < lim ? u : lim)];
  }
  for (int b = 0; b < nb8; ++b){
    unsigned hv[8];
    #pragma unroll
    for (int u = 0; u < 8; ++u) hv[u] = act ? H3[(size_t)sva[u]*20 + p] : 0u;
    float ave = AL[sva[eu]];
    if (b + 1 < nb8){
      const int nbb = base + (b + 1)*8;
      #pragma unroll
      for (int u = 0; u < 8; ++u) svb[u] = col[nbb + u];
    } else if (rem){
      const int tb = base + nb8*8, lim = rem - 1;
      #pragma unroll
      for (int u = 0; u < 8; ++u) svb[u] = col[tb + (u < lim ? u : lim)];
    }
    float ew = __expf(lrelu(ave + ad));
    #pragma unroll
    for (int u = 0; u < 8; ++u){
      float e = __shfl(ew, u, 32);         // segment-relative within 32 lanes
      l += e;
      accL = fmaf(e, bflo(hv[u]), accL);
      accH = fmaf(e, bfhi(hv[u]), accH);
    }
    #pragma unroll
    for (int u = 0; u < 8; ++u) sva[u] = svb[u];
  }
  if (rem){
    unsigned hv[8];
    #pragma unroll
    for (int u = 0; u < 8; ++u) hv[u] = act ? H3[(size_t)sva[u]*20 + p] : 0u;
    float ave = AL[sva[eu]];
    float ew = __expf(lrelu(ave + ad));
    #pragma unroll
    for (int u = 0; u < 8; ++u){
      float e = (u < rem) ? __shfl(ew, u, 32) : 0.f;
      l += e;
      accL = fmaf(e, bflo(hv[u]), accL);
      accH = fmaf(e, bfhi(hv[u]), accH);
    }
  }

  const float rl = 1.f / l;
  const int c0 = 2*p;
  float z0 = act ? (accL*rl + ldf(b3, c0,     isbf)) : NEGBIG;
  float z1 = act ? (accH*rl + ldf(b3, c0 + 1, isbf)) : NEGBIG;
  float mx = fmaxf(z0, z1);
  #pragma unroll
  for (int off = 1; off < 32; off <<= 1) mx = fmaxf(mx, __shfl_xor(mx, off));
  float pp = act ? (__expf(z0 - mx) + __expf(z1 - mx)) : 0.f;
  float sum = pp;
  #pragma unroll
  for (int off = 1; off < 32; off <<= 1) sum += __shfl_xor(sum, off);
  if (act){
    float lg = __logf(sum);
    float r0 = z0 - mx - lg, r1 = z1 - mx - lg;
    if (isbf) ((unsigned*)out)[(size_t)node*20 + p] = pk(r0, r1);
    else      ((float2*)out)[(size_t)node*20 + p] = make_float2(r0, r1);
  }
}

// ---------------- launch ----------------
extern "C" void kernel_launch(void* const* d_in, const int* in_sizes, int n_in,
                              void* d_out, int out_size, void* d_ws, size_t ws_size,
                              hipStream_t stream)
{
  (void)n_in; (void)out_size; (void)ws_size;
  const void* x    = d_in[0];
  const int*  ei   = (const int*)d_in[1];
  const void* W1   = d_in[2];
  const void* as1  = d_in[3];
  const void* ad1  = d_in[4];
  const void* b1   = d_in[5];
  const void* W2   = d_in[6];
  const void* as2  = d_in[7];
  const void* ad2  = d_in[8];
  const void* b2   = d_in[9];
  const void* W3   = d_in[10];
  const void* as3  = d_in[11];
  const void* ad3  = d_in[12];
  const void* b3   = d_in[13];
  const void* bn1g = d_in[14];
  const void* bn1b = d_in[15];
  const void* bn1m = d_in[16];
  const void* bn1v = d_in[17];
  const void* bn2g = d_in[18];
  const void* bn2b = d_in[19];
  const void* bn2m = d_in[20];
  const void* bn2v = d_in[21];

  const int N  = in_sizes[0] / 128;
  const int E  = in_sizes[1] / 2;
  const int ntiles = (N + 15) / 16;

  char* w = (char*)d_ws;
  size_t off = 0;
  auto alloc = [&](size_t bytes)->char*{
    char* p = w + off; off = (off + bytes + 255) & ~(size_t)255; return p;
  };
  unsigned* H2A = (unsigned*)alloc((size_t)N*64*4);   // packed bf16 pairs
  unsigned* H2B = (unsigned*)alloc((size_t)N*64*4);
  unsigned* H3p = (unsigned*)alloc((size_t)N*20*4);
  float* AL   = (float*)alloc((size_t)N*4*4);
  float* AD   = (float*)alloc((size_t)N*4*4);
  int*   cnt   = (int*)alloc((size_t)N*4);
  int*   start = (int*)alloc((size_t)N*4);
  int*   col   = (int*)alloc((size_t)E*4);
  int2*  ebuf  = (int2*)alloc((size_t)E*8);
  unsigned short* WT1 = (unsigned short*)alloc(16384*2);
  unsigned short* WT2 = (unsigned short*)alloc(16384*2);
  unsigned short* WT3 = (unsigned short*)alloc(48*128*2);
  int*   bcnt  = (int*)alloc(1024);
  int*   bstart= (int*)alloc(1024);
  int*   bpos  = (int*)alloc(1024);
  int*   flag  = (int*)alloc(256);

  const int* srcp = ei;
  const int* dstp = ei + E;

  const int nbCH = (E + 4095)/4096;
  const int NB = (N + 511) >> BSHIFT;     // buckets of 512 nodes
  const int bb = (N + 3)/4;               // agg4: 1 node/wave, 4 waves/block
  const int bb1 = (N + 7)/8;              // agg1: 2 nodes/wave, 8 nodes/block
  int g1 = ntiles;                        // 1 tile/block (no LDS, cheap setup)
  int g3 = (ntiles + 3)/4; if (g3 > 800) g3 = 800;

  // CSR build: bucket counting sort, zero random device atomics
  init_detect<<<1,256,0,stream>>>(bcnt, (const unsigned short*)W1, flag);
  wtrans<<<64,256,0,stream>>>(W1, W2, W3, flag, WT1, WT2, WT3);
  hist<<<nbCH,256,0,stream>>>(dstp, bcnt, E, N);
  bscan<<<1,256,0,stream>>>(bcnt, bstart, bpos);
  bres<<<nbCH,256,0,stream>>>(srcp, dstp, bpos, ebuf, E, N);
  bfinal<<<NB,256,0,stream>>>(ebuf, bstart, bpos, cnt, start, col, N);

  // layer 1
  gemm_al_mfma<<<g1,256,0,stream>>>(x, 0, WT1, as1, ad1, flag, H2A, AL, AD, N, ntiles);
  agg4<<<bb,256,0,stream>>>(H2A, AL, AD, cnt, start, col,
                            b1, bn1g, bn1b, bn1m, bn1v, flag, H2B, N);
  // layer 2
  gemm_al_mfma<<<g1,256,0,stream>>>(H2B, 1, WT2, as2, ad2, flag, H2A, AL, AD, N, ntiles);
  agg4<<<bb,256,0,stream>>>(H2A, AL, AD, cnt, start, col,
                            b2, bn2g, bn2b, bn2m, bn2v, flag, H2B, N);
  // layer 3
  gemm3_mfma<<<g3,256,0,stream>>>((const unsigned*)H2B, WT3, as3, ad3, flag, H3p, AL, AD, N, ntiles);
  agg1<<<bb1,256,0,stream>>>(H3p, AL, AD, cnt, start, col, b3, flag, d_out, N);
}